// Round 1
// baseline (1646.246 us; speedup 1.0000x reference)
//
#include <hip/hip_runtime.h>
#include <cstddef>

#define NNODES 25000
#define NEDGES 400000

__device__ __forceinline__ float clip100(float x) {
    return fminf(fmaxf(x, -100.0f), 100.0f);
}
__device__ __forceinline__ float silu_f(float x) {
    return x / (1.0f + __expf(-x));
}

// ---------------------------------------------------------------------------
// Kernel 1: x = silu(s @ Wi1 + bi1) @ Wi2 + bi2        (per node, 128->128->384)
// 256 threads = 4 waves; wave g owns nodes (blockIdx*8 + 2g, +2g+1).
// Lane l owns output columns {l + 64*i}. All LDS reads are wave-uniform
// broadcasts; weight loads are lane-coalesced 256B segments.
// ---------------------------------------------------------------------------
__global__ __launch_bounds__(256, 4) void k_node_mlp(
    const float* __restrict__ s,
    const float* __restrict__ Wi1, const float* __restrict__ bi1,
    const float* __restrict__ Wi2, const float* __restrict__ bi2,
    float* __restrict__ x)
{
    __shared__ __align__(16) float s_lds[8][128];
    __shared__ __align__(16) float h_lds[8][128];
    const int tid = threadIdx.x;
    const int g = tid >> 6;
    const int l = tid & 63;
    const int n0 = 2 * g, n1 = n0 + 1;
    const long gn0 = (long)blockIdx.x * 8 + n0;
    const long gn1 = gn0 + 1;

    // stage s rows (wave-local)
    #pragma unroll
    for (int i = 0; i < 2; ++i) {
        int h = l + 64 * i;
        s_lds[n0][h] = s[gn0 * 128 + h];
        s_lds[n1][h] = s[gn1 * 128 + h];
    }

    // layer 1: O=128, lane owns o = l, l+64
    float accA[2][2];
    accA[0][0] = accA[1][0] = bi1[l];
    accA[0][1] = accA[1][1] = bi1[l + 64];
    #pragma unroll 4
    for (int k = 0; k < 128; ++k) {
        float w0 = Wi1[k * 128 + l];
        float w1 = Wi1[k * 128 + l + 64];
        float i0 = s_lds[n0][k];
        float i1 = s_lds[n1][k];
        accA[0][0] = fmaf(i0, w0, accA[0][0]);
        accA[0][1] = fmaf(i0, w1, accA[0][1]);
        accA[1][0] = fmaf(i1, w0, accA[1][0]);
        accA[1][1] = fmaf(i1, w1, accA[1][1]);
    }
    h_lds[n0][l]      = silu_f(accA[0][0]);
    h_lds[n0][l + 64] = silu_f(accA[0][1]);
    h_lds[n1][l]      = silu_f(accA[1][0]);
    h_lds[n1][l + 64] = silu_f(accA[1][1]);

    // layer 2: O=384, lane owns o = l + 64*i, i<6
    float accB[2][6];
    #pragma unroll
    for (int i = 0; i < 6; ++i) {
        float b = bi2[l + 64 * i];
        accB[0][i] = b; accB[1][i] = b;
    }
    #pragma unroll 4
    for (int k = 0; k < 128; ++k) {
        float i0 = h_lds[n0][k];
        float i1 = h_lds[n1][k];
        #pragma unroll
        for (int i = 0; i < 6; ++i) {
            float w = Wi2[k * 384 + l + 64 * i];
            accB[0][i] = fmaf(i0, w, accB[0][i]);
            accB[1][i] = fmaf(i1, w, accB[1][i]);
        }
    }
    #pragma unroll
    for (int i = 0; i < 6; ++i) {
        x[gn0 * 384 + l + 64 * i] = accB[0][i];
        x[gn1 * 384 + l + 64 * i] = accB[1][i];
    }
}

// ---------------------------------------------------------------------------
// Kernel 2: per-edge messages + segment_sum via HW fp32 atomics.
// acc layout per node: [ds(128) | dv0(128) | dv1(128) | dv2(128)]
// 256 threads handle 2 edges (128 lanes per edge, lane = h channel).
// ---------------------------------------------------------------------------
__global__ __launch_bounds__(256, 4) void k_edge(
    const float* __restrict__ x, const float* __restrict__ v,
    const float* __restrict__ dir_ij, const float* __restrict__ Wij,
    const int* __restrict__ senders, const int* __restrict__ receivers,
    float* __restrict__ acc)
{
    const long e = (long)blockIdx.x * 2 + (threadIdx.x >> 7);
    const int h = threadIdx.x & 127;
    const int se = senders[e];
    const int re = receivers[e];
    const float d0 = dir_ij[e * 3 + 0];
    const float d1 = dir_ij[e * 3 + 1];
    const float d2 = dir_ij[e * 3 + 2];
    const float* __restrict__ wrow = Wij + e * 384;
    const float* __restrict__ xrow = x + (long)re * 384;
    const float* __restrict__ vrow = v + (long)re * 384;

    float ds = wrow[h]       * xrow[h];
    float a  = wrow[128 + h] * xrow[128 + h];
    float b  = wrow[256 + h] * xrow[256 + h];
    float dv0 = fmaf(a, d0, b * vrow[h]);
    float dv1 = fmaf(a, d1, b * vrow[128 + h]);
    float dv2 = fmaf(a, d2, b * vrow[256 + h]);

    float* arow = acc + (long)se * 512;
    unsafeAtomicAdd(arow + h,       ds);
    unsafeAtomicAdd(arow + 128 + h, dv0);
    unsafeAtomicAdd(arow + 256 + h, dv1);
    unsafeAtomicAdd(arow + 384 + h, dv2);
}

// ---------------------------------------------------------------------------
// Kernel 3: node update.
//   s += clip(ds); v += clip(dv)
//   v_l, v_r = split(v @ Wv); vnorm = sqrt(sum_d v_r^2 + eps)
//   ds_u, dv_u, dsv = split(mlp(concat(s, vnorm)))
//   s += clip(ds_u + dsv * sum_d(v_r*v_l)); v += clip(v_l * dv_u)
// Wave g owns nodes 2g, 2g+1; lane l owns columns {l + 64*i}.
// After the v@Wv step everything is lane-local -> no __syncthreads anywhere.
// ---------------------------------------------------------------------------
__global__ __launch_bounds__(256, 4) void k_update(
    const float* __restrict__ s_in, const float* __restrict__ v_in,
    const float* __restrict__ acc,
    const float* __restrict__ Wm1, const float* __restrict__ bm1,
    const float* __restrict__ Wm2, const float* __restrict__ bm2,
    const float* __restrict__ Wv,
    float* __restrict__ s_out, float* __restrict__ v_out)
{
    __shared__ __align__(16) float ts[8][256];     // [s+ds | vnorm]
    __shared__ __align__(16) float v_cur[8][384];  // v + clip(dv)
    __shared__ __align__(16) float hid[8][128];
    const int tid = threadIdx.x;
    const int g = tid >> 6;
    const int l = tid & 63;
    const int n0 = 2 * g, n1 = n0 + 1;
    const long gn0 = (long)blockIdx.x * 8 + n0;
    const long gn1 = gn0 + 1;

    // stage s + clip(ds)
    #pragma unroll
    for (int i = 0; i < 2; ++i) {
        int h = l + 64 * i;
        ts[n0][h] = s_in[gn0 * 128 + h] + clip100(acc[gn0 * 512 + h]);
        ts[n1][h] = s_in[gn1 * 128 + h] + clip100(acc[gn1 * 512 + h]);
    }
    // stage v + clip(dv)
    float vreg[2][6];
    #pragma unroll
    for (int i = 0; i < 6; ++i) {
        int r = l + 64 * i;
        vreg[0][i] = v_in[gn0 * 384 + r] + clip100(acc[gn0 * 512 + 128 + r]);
        vreg[1][i] = v_in[gn1 * 384 + r] + clip100(acc[gn1 * 512 + 128 + r]);
        v_cur[n0][r] = vreg[0][i];
        v_cur[n1][r] = vreg[1][i];
    }

    // v @ Wv : O=256. lane owns o = l + 64*i; i<2 -> v_l[h=l+64i], i>=2 -> v_r.
    float aV[2][3][4];
    #pragma unroll
    for (int j = 0; j < 2; ++j)
        #pragma unroll
        for (int d = 0; d < 3; ++d)
            #pragma unroll
            for (int i = 0; i < 4; ++i) aV[j][d][i] = 0.0f;
    #pragma unroll 4
    for (int k = 0; k < 128; ++k) {
        float w[4];
        #pragma unroll
        for (int i = 0; i < 4; ++i) w[i] = Wv[k * 256 + l + 64 * i];
        #pragma unroll
        for (int d = 0; d < 3; ++d) {
            float i0 = v_cur[n0][d * 128 + k];
            float i1 = v_cur[n1][d * 128 + k];
            #pragma unroll
            for (int i = 0; i < 4; ++i) {
                aV[0][d][i] = fmaf(i0, w[i], aV[0][d][i]);
                aV[1][d][i] = fmaf(i1, w[i], aV[1][d][i]);
            }
        }
    }

    // vnorm -> ts[:,128:], vv = sum_d v_r*v_l (lane-local, kept in regs)
    float vv[2][2];
    #pragma unroll
    for (int j = 0; j < 2; ++j) {
        int nn = (j == 0) ? n0 : n1;
        #pragma unroll
        for (int i = 0; i < 2; ++i) {
            int h = l + 64 * i;
            float l0 = aV[j][0][i],     l1 = aV[j][1][i],     l2 = aV[j][2][i];
            float r0 = aV[j][0][i + 2], r1 = aV[j][1][i + 2], r2 = aV[j][2][i + 2];
            ts[nn][128 + h] = sqrtf(fmaf(r0, r0, fmaf(r1, r1, r2 * r2)) + 1e-8f);
            vv[j][i] = fmaf(r0, l0, fmaf(r1, l1, r2 * l2));
        }
    }

    // mixing layer 1: K=256 -> O=128 (silu)
    float aM[2][2];
    aM[0][0] = aM[1][0] = bm1[l];
    aM[0][1] = aM[1][1] = bm1[l + 64];
    #pragma unroll 4
    for (int k = 0; k < 256; ++k) {
        float w0 = Wm1[k * 128 + l];
        float w1 = Wm1[k * 128 + l + 64];
        float i0 = ts[n0][k];
        float i1 = ts[n1][k];
        aM[0][0] = fmaf(i0, w0, aM[0][0]);
        aM[0][1] = fmaf(i0, w1, aM[0][1]);
        aM[1][0] = fmaf(i1, w0, aM[1][0]);
        aM[1][1] = fmaf(i1, w1, aM[1][1]);
    }
    hid[n0][l]      = silu_f(aM[0][0]);
    hid[n0][l + 64] = silu_f(aM[0][1]);
    hid[n1][l]      = silu_f(aM[1][0]);
    hid[n1][l + 64] = silu_f(aM[1][1]);

    // mixing layer 2: K=128 -> O=384. i<2: ds_u, i in [2,4): dv_u, i in [4,6): dsv
    float aB[2][6];
    #pragma unroll
    for (int i = 0; i < 6; ++i) {
        float b = bm2[l + 64 * i];
        aB[0][i] = b; aB[1][i] = b;
    }
    #pragma unroll 4
    for (int k = 0; k < 128; ++k) {
        float i0 = hid[n0][k];
        float i1 = hid[n1][k];
        #pragma unroll
        for (int i = 0; i < 6; ++i) {
            float w = Wm2[k * 384 + l + 64 * i];
            aB[0][i] = fmaf(i0, w, aB[0][i]);
            aB[1][i] = fmaf(i1, w, aB[1][i]);
        }
    }

    // final updates (all lane-local)
    #pragma unroll
    for (int j = 0; j < 2; ++j) {
        int nn = (j == 0) ? n0 : n1;
        long gn = (j == 0) ? gn0 : gn1;
        #pragma unroll
        for (int i = 0; i < 2; ++i) {
            int h = l + 64 * i;
            s_out[gn * 128 + h] = ts[nn][h] + clip100(aB[j][i] + aB[j][4 + i] * vv[j][i]);
        }
        #pragma unroll
        for (int i = 0; i < 6; ++i) {
            int r = l + 64 * i;
            int d = i >> 1;
            int b = i & 1;  // h = l + 64*b
            float vl = aV[j][d][b];
            float dvu = aB[j][2 + b];
            v_out[gn * 384 + r] = vreg[j][i] + clip100(vl * dvu);
        }
    }
}

extern "C" void kernel_launch(void* const* d_in, const int* in_sizes, int n_in,
                              void* d_out, int out_size, void* d_ws, size_t ws_size,
                              hipStream_t stream) {
    const float* s   = (const float*)d_in[0];
    const float* v   = (const float*)d_in[1];
    const float* dir = (const float*)d_in[2];
    const float* Wij = (const float*)d_in[3];
    const float* Wi1 = (const float*)d_in[4];
    const float* bi1 = (const float*)d_in[5];
    const float* Wi2 = (const float*)d_in[6];
    const float* bi2 = (const float*)d_in[7];
    const float* Wm1 = (const float*)d_in[8];
    const float* bm1 = (const float*)d_in[9];
    const float* Wm2 = (const float*)d_in[10];
    const float* bm2 = (const float*)d_in[11];
    const float* Wv  = (const float*)d_in[12];
    const int* senders   = (const int*)d_in[13];
    const int* receivers = (const int*)d_in[14];

    float* xbuf = (float*)d_ws;                       // NNODES*384 floats (38.4 MB)
    float* accb = xbuf + (size_t)NNODES * 384;        // NNODES*512 floats (51.2 MB)
    float* s_out = (float*)d_out;
    float* v_out = s_out + (size_t)NNODES * 128;

    hipMemsetAsync(accb, 0, (size_t)NNODES * 512 * sizeof(float), stream);
    k_node_mlp<<<NNODES / 8, 256, 0, stream>>>(s, Wi1, bi1, Wi2, bi2, xbuf);
    k_edge<<<NEDGES / 2, 256, 0, stream>>>(xbuf, v, dir, Wij, senders, receivers, accb);
    k_update<<<NNODES / 8, 256, 0, stream>>>(s, v, accb, Wm1, bm1, Wm2, bm2, Wv,
                                             s_out, v_out);
}

// Round 2
// 1377.239 us; speedup vs baseline: 1.1953x; 1.1953x over previous
//
#include <hip/hip_runtime.h>
#include <cstddef>

#define NNODES 25000
#define NEDGES 400000

__device__ __forceinline__ float clip100(float x) {
    return fminf(fmaxf(x, -100.0f), 100.0f);
}
__device__ __forceinline__ float silu_f(float x) {
    return x / (1.0f + __expf(-x));
}

// ---------------------------------------------------------------------------
// CSR build: histogram -> scan -> scatter.  Sorting edges by sender lets the
// edge kernel accumulate in registers (plain stores) instead of 205M fp32
// atomics that were writing through to HBM (819 MB of WRITE_SIZE in round 1).
// ---------------------------------------------------------------------------
__global__ void k_hist(const int* __restrict__ senders, int* __restrict__ counts)
{
    int e = blockIdx.x * 256 + threadIdx.x;
    if (e < NEDGES) atomicAdd(&counts[senders[e]], 1);
}

__global__ void k_scan(const int* __restrict__ counts,
                       int* __restrict__ rowstart, int* __restrict__ cursor)
{
    __shared__ int buf[1024];
    __shared__ int carry_s;
    const int tid = threadIdx.x;
    if (tid == 0) carry_s = 0;
    __syncthreads();
    const int nchunks = (NNODES + 1023) / 1024;
    for (int c = 0; c < nchunks; ++c) {
        int i = c * 1024 + tid;
        int val = (i < NNODES) ? counts[i] : 0;
        buf[tid] = val;
        __syncthreads();
        // inclusive Hillis-Steele scan over 1024
        #pragma unroll
        for (int off = 1; off < 1024; off <<= 1) {
            int t = (tid >= off) ? buf[tid - off] : 0;
            __syncthreads();
            buf[tid] += t;
            __syncthreads();
        }
        int incl = buf[tid];
        int excl = incl - val + carry_s;
        if (i < NNODES) { rowstart[i] = excl; cursor[i] = excl; }
        int chunk_total = buf[1023];
        __syncthreads();                 // everyone read carry_s / buf
        if (tid == 0) carry_s += chunk_total;
        __syncthreads();
    }
    if (tid == 0) rowstart[NNODES] = carry_s;
}

__global__ void k_scatter(const int* __restrict__ senders,
                          int* __restrict__ cursor, int* __restrict__ eids)
{
    int e = blockIdx.x * 256 + threadIdx.x;
    if (e < NEDGES) {
        int pos = atomicAdd(&cursor[senders[e]], 1);
        eids[pos] = e;
    }
}

// ---------------------------------------------------------------------------
// Kernel 1: x = silu(s @ Wi1 + bi1) @ Wi2 + bi2        (per node, 128->128->384)
// ---------------------------------------------------------------------------
__global__ __launch_bounds__(256, 4) void k_node_mlp(
    const float* __restrict__ s,
    const float* __restrict__ Wi1, const float* __restrict__ bi1,
    const float* __restrict__ Wi2, const float* __restrict__ bi2,
    float* __restrict__ x)
{
    __shared__ __align__(16) float s_lds[8][128];
    __shared__ __align__(16) float h_lds[8][128];
    const int tid = threadIdx.x;
    const int g = tid >> 6;
    const int l = tid & 63;
    const int n0 = 2 * g, n1 = n0 + 1;
    const long gn0 = (long)blockIdx.x * 8 + n0;
    const long gn1 = gn0 + 1;

    #pragma unroll
    for (int i = 0; i < 2; ++i) {
        int h = l + 64 * i;
        s_lds[n0][h] = s[gn0 * 128 + h];
        s_lds[n1][h] = s[gn1 * 128 + h];
    }

    float accA[2][2];
    accA[0][0] = accA[1][0] = bi1[l];
    accA[0][1] = accA[1][1] = bi1[l + 64];
    #pragma unroll 4
    for (int k = 0; k < 128; ++k) {
        float w0 = Wi1[k * 128 + l];
        float w1 = Wi1[k * 128 + l + 64];
        float i0 = s_lds[n0][k];
        float i1 = s_lds[n1][k];
        accA[0][0] = fmaf(i0, w0, accA[0][0]);
        accA[0][1] = fmaf(i0, w1, accA[0][1]);
        accA[1][0] = fmaf(i1, w0, accA[1][0]);
        accA[1][1] = fmaf(i1, w1, accA[1][1]);
    }
    h_lds[n0][l]      = silu_f(accA[0][0]);
    h_lds[n0][l + 64] = silu_f(accA[0][1]);
    h_lds[n1][l]      = silu_f(accA[1][0]);
    h_lds[n1][l + 64] = silu_f(accA[1][1]);

    float accB[2][6];
    #pragma unroll
    for (int i = 0; i < 6; ++i) {
        float b = bi2[l + 64 * i];
        accB[0][i] = b; accB[1][i] = b;
    }
    #pragma unroll 4
    for (int k = 0; k < 128; ++k) {
        float i0 = h_lds[n0][k];
        float i1 = h_lds[n1][k];
        #pragma unroll
        for (int i = 0; i < 6; ++i) {
            float w = Wi2[k * 384 + l + 64 * i];
            accB[0][i] = fmaf(i0, w, accB[0][i]);
            accB[1][i] = fmaf(i1, w, accB[1][i]);
        }
    }
    #pragma unroll
    for (int i = 0; i < 6; ++i) {
        x[gn0 * 384 + l + 64 * i] = accB[0][i];
        x[gn1 * 384 + l + 64 * i] = accB[1][i];
    }
}

// ---------------------------------------------------------------------------
// Kernel 2 (new): sorted edge aggregation.  One wave per sender node; lane l
// owns channels {l, l+64}.  All accumulation in registers, plain coalesced
// stores to acc (no atomics, no memset).
// acc layout per node: [ds(128) | dv0(128) | dv1(128) | dv2(128)]
// ---------------------------------------------------------------------------
__global__ __launch_bounds__(256, 8) void k_edge_sorted(
    const float* __restrict__ x, const float* __restrict__ v,
    const float* __restrict__ dir_ij, const float* __restrict__ Wij,
    const int* __restrict__ receivers,
    const int* __restrict__ rowstart, const int* __restrict__ eids,
    float* __restrict__ acc)
{
    const int wave = threadIdx.x >> 6;
    const int l = threadIdx.x & 63;
    const int n = blockIdx.x * 4 + wave;
    if (n >= NNODES) return;

    float ds0 = 0.0f, ds1 = 0.0f;
    float dva0 = 0.0f, dva1 = 0.0f, dva2 = 0.0f;   // dv[d][h0=l]
    float dvb0 = 0.0f, dvb1 = 0.0f, dvb2 = 0.0f;   // dv[d][h1=l+64]

    const int jb = rowstart[n];
    const int je = rowstart[n + 1];
    for (int j = jb; j < je; ++j) {
        const int e  = eids[j];
        const int re = receivers[e];
        const float* __restrict__ wr = Wij + (long)e * 384;
        const float* __restrict__ xr = x + (long)re * 384;
        const float* __restrict__ vr = v + (long)re * 384;
        const float d0 = dir_ij[e * 3 + 0];
        const float d1 = dir_ij[e * 3 + 1];
        const float d2 = dir_ij[e * 3 + 2];

        float w0a = wr[l],       w1a = wr[128 + l], w2a = wr[256 + l];
        float w0b = wr[64 + l],  w1b = wr[192 + l], w2b = wr[320 + l];
        float x0a = xr[l],       x1a = xr[128 + l], x2a = xr[256 + l];
        float x0b = xr[64 + l],  x1b = xr[192 + l], x2b = xr[320 + l];
        float va0 = vr[l],       va1 = vr[128 + l], va2 = vr[256 + l];
        float vb0 = vr[64 + l],  vb1 = vr[192 + l], vb2 = vr[320 + l];

        ds0 = fmaf(w0a, x0a, ds0);
        ds1 = fmaf(w0b, x0b, ds1);
        float aa = w1a * x1a, ba = w2a * x2a;
        float ab = w1b * x1b, bb = w2b * x2b;
        dva0 = fmaf(aa, d0, fmaf(ba, va0, dva0));
        dva1 = fmaf(aa, d1, fmaf(ba, va1, dva1));
        dva2 = fmaf(aa, d2, fmaf(ba, va2, dva2));
        dvb0 = fmaf(ab, d0, fmaf(bb, vb0, dvb0));
        dvb1 = fmaf(ab, d1, fmaf(bb, vb1, dvb1));
        dvb2 = fmaf(ab, d2, fmaf(bb, vb2, dvb2));
    }

    float* __restrict__ arow = acc + (long)n * 512;
    arow[l]        = ds0;   arow[64 + l]  = ds1;
    arow[128 + l]  = dva0;  arow[192 + l] = dvb0;
    arow[256 + l]  = dva1;  arow[320 + l] = dvb1;
    arow[384 + l]  = dva2;  arow[448 + l] = dvb2;
}

// ---------------------------------------------------------------------------
// Kernel 3: node update (unchanged from round 1).
// ---------------------------------------------------------------------------
__global__ __launch_bounds__(256, 4) void k_update(
    const float* __restrict__ s_in, const float* __restrict__ v_in,
    const float* __restrict__ acc,
    const float* __restrict__ Wm1, const float* __restrict__ bm1,
    const float* __restrict__ Wm2, const float* __restrict__ bm2,
    const float* __restrict__ Wv,
    float* __restrict__ s_out, float* __restrict__ v_out)
{
    __shared__ __align__(16) float ts[8][256];     // [s+ds | vnorm]
    __shared__ __align__(16) float v_cur[8][384];  // v + clip(dv)
    __shared__ __align__(16) float hid[8][128];
    const int tid = threadIdx.x;
    const int g = tid >> 6;
    const int l = tid & 63;
    const int n0 = 2 * g, n1 = n0 + 1;
    const long gn0 = (long)blockIdx.x * 8 + n0;
    const long gn1 = gn0 + 1;

    #pragma unroll
    for (int i = 0; i < 2; ++i) {
        int h = l + 64 * i;
        ts[n0][h] = s_in[gn0 * 128 + h] + clip100(acc[gn0 * 512 + h]);
        ts[n1][h] = s_in[gn1 * 128 + h] + clip100(acc[gn1 * 512 + h]);
    }
    float vreg[2][6];
    #pragma unroll
    for (int i = 0; i < 6; ++i) {
        int r = l + 64 * i;
        vreg[0][i] = v_in[gn0 * 384 + r] + clip100(acc[gn0 * 512 + 128 + r]);
        vreg[1][i] = v_in[gn1 * 384 + r] + clip100(acc[gn1 * 512 + 128 + r]);
        v_cur[n0][r] = vreg[0][i];
        v_cur[n1][r] = vreg[1][i];
    }

    float aV[2][3][4];
    #pragma unroll
    for (int j = 0; j < 2; ++j)
        #pragma unroll
        for (int d = 0; d < 3; ++d)
            #pragma unroll
            for (int i = 0; i < 4; ++i) aV[j][d][i] = 0.0f;
    #pragma unroll 4
    for (int k = 0; k < 128; ++k) {
        float w[4];
        #pragma unroll
        for (int i = 0; i < 4; ++i) w[i] = Wv[k * 256 + l + 64 * i];
        #pragma unroll
        for (int d = 0; d < 3; ++d) {
            float i0 = v_cur[n0][d * 128 + k];
            float i1 = v_cur[n1][d * 128 + k];
            #pragma unroll
            for (int i = 0; i < 4; ++i) {
                aV[0][d][i] = fmaf(i0, w[i], aV[0][d][i]);
                aV[1][d][i] = fmaf(i1, w[i], aV[1][d][i]);
            }
        }
    }

    float vv[2][2];
    #pragma unroll
    for (int j = 0; j < 2; ++j) {
        int nn = (j == 0) ? n0 : n1;
        #pragma unroll
        for (int i = 0; i < 2; ++i) {
            int h = l + 64 * i;
            float l0 = aV[j][0][i],     l1 = aV[j][1][i],     l2 = aV[j][2][i];
            float r0 = aV[j][0][i + 2], r1 = aV[j][1][i + 2], r2 = aV[j][2][i + 2];
            ts[nn][128 + h] = sqrtf(fmaf(r0, r0, fmaf(r1, r1, r2 * r2)) + 1e-8f);
            vv[j][i] = fmaf(r0, l0, fmaf(r1, l1, r2 * l2));
        }
    }

    float aM[2][2];
    aM[0][0] = aM[1][0] = bm1[l];
    aM[0][1] = aM[1][1] = bm1[l + 64];
    #pragma unroll 4
    for (int k = 0; k < 256; ++k) {
        float w0 = Wm1[k * 128 + l];
        float w1 = Wm1[k * 128 + l + 64];
        float i0 = ts[n0][k];
        float i1 = ts[n1][k];
        aM[0][0] = fmaf(i0, w0, aM[0][0]);
        aM[0][1] = fmaf(i0, w1, aM[0][1]);
        aM[1][0] = fmaf(i1, w0, aM[1][0]);
        aM[1][1] = fmaf(i1, w1, aM[1][1]);
    }
    hid[n0][l]      = silu_f(aM[0][0]);
    hid[n0][l + 64] = silu_f(aM[0][1]);
    hid[n1][l]      = silu_f(aM[1][0]);
    hid[n1][l + 64] = silu_f(aM[1][1]);

    float aB[2][6];
    #pragma unroll
    for (int i = 0; i < 6; ++i) {
        float b = bm2[l + 64 * i];
        aB[0][i] = b; aB[1][i] = b;
    }
    #pragma unroll 4
    for (int k = 0; k < 128; ++k) {
        float i0 = hid[n0][k];
        float i1 = hid[n1][k];
        #pragma unroll
        for (int i = 0; i < 6; ++i) {
            float w = Wm2[k * 384 + l + 64 * i];
            aB[0][i] = fmaf(i0, w, aB[0][i]);
            aB[1][i] = fmaf(i1, w, aB[1][i]);
        }
    }

    #pragma unroll
    for (int j = 0; j < 2; ++j) {
        int nn = (j == 0) ? n0 : n1;
        long gn = (j == 0) ? gn0 : gn1;
        #pragma unroll
        for (int i = 0; i < 2; ++i) {
            int h = l + 64 * i;
            s_out[gn * 128 + h] = ts[nn][h] + clip100(aB[j][i] + aB[j][4 + i] * vv[j][i]);
        }
        #pragma unroll
        for (int i = 0; i < 6; ++i) {
            int r = l + 64 * i;
            int d = i >> 1;
            int b = i & 1;
            float vl = aV[j][d][b];
            float dvu = aB[j][2 + b];
            v_out[gn * 384 + r] = vreg[j][i] + clip100(vl * dvu);
        }
    }
}

extern "C" void kernel_launch(void* const* d_in, const int* in_sizes, int n_in,
                              void* d_out, int out_size, void* d_ws, size_t ws_size,
                              hipStream_t stream) {
    const float* s   = (const float*)d_in[0];
    const float* v   = (const float*)d_in[1];
    const float* dir = (const float*)d_in[2];
    const float* Wij = (const float*)d_in[3];
    const float* Wi1 = (const float*)d_in[4];
    const float* bi1 = (const float*)d_in[5];
    const float* Wi2 = (const float*)d_in[6];
    const float* bi2 = (const float*)d_in[7];
    const float* Wm1 = (const float*)d_in[8];
    const float* bm1 = (const float*)d_in[9];
    const float* Wm2 = (const float*)d_in[10];
    const float* bm2 = (const float*)d_in[11];
    const float* Wv  = (const float*)d_in[12];
    const int* senders   = (const int*)d_in[13];
    const int* receivers = (const int*)d_in[14];

    float* xbuf = (float*)d_ws;                       // NNODES*384 floats
    float* accb = xbuf + (size_t)NNODES * 384;        // NNODES*512 floats
    int* counts   = (int*)(accb + (size_t)NNODES * 512);  // NNODES
    int* rowstart = counts + NNODES;                      // NNODES+1 (pad to 25008)
    int* cursor   = rowstart + NNODES + 8;                // NNODES
    int* eids     = cursor + NNODES;                      // NEDGES
    float* s_out = (float*)d_out;
    float* v_out = s_out + (size_t)NNODES * 128;

    hipMemsetAsync(counts, 0, (size_t)NNODES * sizeof(int), stream);
    k_hist<<<(NEDGES + 255) / 256, 256, 0, stream>>>(senders, counts);
    k_scan<<<1, 1024, 0, stream>>>(counts, rowstart, cursor);
    k_scatter<<<(NEDGES + 255) / 256, 256, 0, stream>>>(senders, cursor, eids);
    k_node_mlp<<<NNODES / 8, 256, 0, stream>>>(s, Wi1, bi1, Wi2, bi2, xbuf);
    k_edge_sorted<<<(NNODES + 3) / 4, 256, 0, stream>>>(
        xbuf, v, dir, Wij, receivers, rowstart, eids, accb);
    k_update<<<NNODES / 8, 256, 0, stream>>>(s, v, accb, Wm1, bm1, Wm2, bm2, Wv,
                                             s_out, v_out);
}